// Round 2
// baseline (14936.562 us; speedup 1.0000x reference)
//
#include <hip/hip_runtime.h>

#define BB 64
#define NN 128
#define DD 512
#define TD3 1536
#define NBLK 128
#define NTHR 512

typedef unsigned short u16;
typedef __attribute__((ext_vector_type(8))) __bf16 bf16x8;
typedef __attribute__((ext_vector_type(4))) float f32x4;

__device__ __forceinline__ float b2f(u16 u) {
    union { unsigned int i; float f; } c; c.i = ((unsigned int)u) << 16; return c.f;
}
__device__ __forceinline__ u16 f2b(float f) {
    union { float f; unsigned int i; } c; c.f = f;
    return (u16)((c.i + 0x7FFFu + ((c.i >> 16) & 1u)) >> 16);
}
__device__ __forceinline__ float sigm(float x) { return 1.f / (1.f + __expf(-x)); }
__device__ __forceinline__ float tanh_(float x) {
    x = fminf(fmaxf(x, -15.f), 15.f);
    float e = __expf(2.f * x);
    return (e - 1.f) / (e + 1.f);
}

// device-scope grid barrier: monotonically increasing counter, target = gen*NBLK
__device__ __forceinline__ void gbar(int* ctr, int target) {
    __syncthreads();
    if (threadIdx.x == 0) {
        __hip_atomic_fetch_add(ctr, 1, __ATOMIC_ACQ_REL, __HIP_MEMORY_SCOPE_AGENT);
        while (__hip_atomic_load(ctr, __ATOMIC_ACQUIRE, __HIP_MEMORY_SCOPE_AGENT) < target) {
            __builtin_amdgcn_s_sleep(2);
        }
    }
    __syncthreads();
}

// elementwise GRU-combine for row j>=1.
// bcb layout (per batch, 6656 f32): [0,512) M | [512,2048) gh_c | [2048,3584) gi_p
//                                   | [3584,5120) gi_c | [5120,6656) gh_p
__device__ __forceinline__ void ew_row(
    int b, int j, const float* feat, const float* bcb, const float* lin_w,
    float* H, float* out, float* hk, float* s_red)
{
    const int t = threadIdx.x, d = t;
    float Mv  = bcb[d];
    float ir  = bcb[3584 + d], iz = bcb[4096 + d], inn = bcb[4608 + d];
    float hr  = bcb[512 + d],  hz = bcb[1024 + d], hn  = bcb[1536 + d];
    float r = sigm(ir + hr), z = sigm(iz + hz);
    float nv = tanh_(inn + r * hn);
    float C = (1.f - z) * nv + z * Mv;
    float gir = bcb[2048 + d], giz = bcb[2560 + d], gin = bcb[3072 + d];
    float ghr = bcb[5120 + d], ghz = bcb[5632 + d], ghn = bcb[6144 + d];
    float r2 = sigm(gir + ghr), z2 = sigm(giz + ghz);
    float n2 = tanh_(gin + r2 * ghn);
    float x = feat[(b * NN + j) * DD + d];
    float P = (1.f - z2) * n2 + z2 * x;
    float Hv = C + P;
    H[(b * NN + j) * DD + d] = Hv;
    out[(b * NN + j) * DD + d] = Hv;
    s_red[t] = Hv * lin_w[DD + d];       // wk
    __syncthreads();
    if (t < 256) s_red[t] += s_red[t + 256];
    __syncthreads();
    if (t < 128) s_red[t] += s_red[t + 128];
    __syncthreads();
    if (t < 64) {
        float p = s_red[t] + s_red[t + 64];
        #pragma unroll
        for (int off = 32; off; off >>= 1) p += __shfl_down(p, off, 64);
        if (t == 0) hk[b * NN + j] = p;
    }
    __syncthreads();
}

__global__ __launch_bounds__(NTHR) void grn_kernel(
    const float* feat, const float* Wi_c, const float* Wh_c, const float* bi_c, const float* bh_c,
    const float* Wi_p, const float* Wh_p, const float* bi_p, const float* bh_p,
    const float* lin_w, const float* lin_b, const float* Wr0, const float* Wr1,
    const int* adj, const int* smask,
    float* out,
    float* H, float* hk, float* q, u16* ublob, u16* mblob, u16* xblob, float* bc,
    u16* WrB, u16* WcB, u16* WxB, int* ctr)
{
    const int t = threadIdx.x, blk = blockIdx.x;
    const int lane = t & 63, wv = t >> 6;
    const int lr = lane & 15, lq = lane >> 4;
    int gen = 0;

    __shared__ float s_red[NTHR];
    __shared__ float s_a[NN], s_w[NN], s_ws[NN];
    __shared__ float s_scal;

    // ===== Ph0: build split-weight blobs, q, xblob row0 =====
    {
        // WrB: 512 rows x 3072, segs [W0hi W0hi W0lo W1hi W1hi W1lo]
        for (int c = blk * 4; c < blk * 4 + 4; ++c) {
            int k = t;
            float w0 = Wr0[c * DD + k], w1 = Wr1[c * DD + k];
            u16 h0 = f2b(w0), l0 = f2b(w0 - b2f(h0));
            u16 h1 = f2b(w1), l1 = f2b(w1 - b2f(h1));
            u16* row = WrB + c * 3072;
            row[k] = h0; row[512 + k] = h0; row[1024 + k] = l0;
            row[1536 + k] = h1; row[2048 + k] = h1; row[2560 + k] = l1;
        }
        // WcB: 3072 rows x 1536 (Wh_c | Wi_p), segs [hi hi lo]
        for (int c = blk * 24; c < blk * 24 + 24; ++c) {
            const float* src = (c < TD3) ? (Wh_c + c * DD) : (Wi_p + (c - TD3) * DD);
            int k = t;
            float w = src[k];
            u16 h = f2b(w), l = f2b(w - b2f(h));
            u16* row = WcB + c * 1536;
            row[k] = h; row[512 + k] = h; row[1024 + k] = l;
        }
        // WxB: 3072 rows x 1536 (Wi_c | Wh_p), segs [hi hi lo]
        for (int c = blk * 24; c < blk * 24 + 24; ++c) {
            const float* src = (c < TD3) ? (Wi_c + c * DD) : (Wh_p + (c - TD3) * DD);
            int k = t;
            float w = src[k];
            u16 h = f2b(w), l = f2b(w - b2f(h));
            u16* row = WxB + c * 1536;
            row[k] = h; row[512 + k] = h; row[1024 + k] = l;
        }
        // q[b,n] = feat[b,n].wq + lin_b
        {
            float linb = lin_b[0];
            float wqf[8];
            #pragma unroll
            for (int jj = 0; jj < 8; ++jj) wqf[jj] = lin_w[lane * 8 + jj];
            for (int rr = 0; rr < 8; ++rr) {
                int row = blk * 64 + wv * 8 + rr;
                const float* fp = feat + row * DD + lane * 8;
                float p = 0.f;
                #pragma unroll
                for (int jj = 0; jj < 8; ++jj) p += fp[jj] * wqf[jj];
                #pragma unroll
                for (int off = 32; off; off >>= 1) p += __shfl_down(p, off, 64);
                if (lane == 0) q[row] = p + linb;
            }
        }
        // xblob for row 0
        if (blk < BB) {
            float x = feat[(blk * NN + 0) * DD + t];
            u16 h = f2b(x);
            xblob[blk * 1536 + t] = h;
            xblob[blk * 1536 + 512 + t] = f2b(x - b2f(h));
            xblob[blk * 1536 + 1024 + t] = h;
        }
    }
    gbar(ctr, ++gen * NBLK);

    // ===== Ph0x: x-gates for row 0 =====
    if (blk >= 16 && blk < 112) {
        int rb = blk - 16;
        int c0 = rb * 32;
        int m0 = (wv >> 1) * 16;
        int n0 = c0 + (wv & 1) * 16;
        int col = n0 + lr;
        f32x4 acc = {0.f, 0.f, 0.f, 0.f};
        const u16* arow = xblob + (m0 + lr) * 1536;
        const u16* brow = WxB + col * 1536;
        for (int ks = 0; ks < 48; ++ks) {
            int kb = ks * 32 + lq * 8;
            bf16x8 av = *(const bf16x8*)(arow + kb);
            bf16x8 bv = *(const bf16x8*)(brow + kb);
            acc = __builtin_amdgcn_mfma_f32_16x16x32_bf16(av, bv, acc, 0, 0, 0);
        }
        float bias = (col < TD3) ? bi_c[col] : bh_p[col - TD3];
        #pragma unroll
        for (int r = 0; r < 4; ++r) {
            int brw = m0 + lq * 4 + r;
            bc[brw * 6656 + 3584 + col] = acc[r] + bias;
        }
    }
    gbar(ctr, ++gen * NBLK);

    // ===== Ph1: row 0 = C0 + P0 =====
    if (blk < BB) {
        int b = blk, d = t;
        const float* bcb = bc + b * 6656;
        float ir = bcb[3584 + d], iz = bcb[4096 + d], inn = bcb[4608 + d];
        float r = sigm(ir + bh_c[d]), z = sigm(iz + bh_c[512 + d]);
        float nv = tanh_(inn + r * bh_c[1024 + d]);
        float C = (1.f - z) * nv;                    // h = 0
        float ghr = bcb[5120 + d], ghz = bcb[5632 + d], ghn = bcb[6144 + d];
        float r2 = sigm(bi_p[d] + ghr), z2 = sigm(bi_p[512 + d] + ghz);
        float n2 = tanh_(bi_p[1024 + d] + r2 * ghn);
        float x = feat[(b * NN + 0) * DD + d];
        float P = (1.f - z2) * n2 + z2 * x;          // h = x0
        float Hv = C + P;
        H[(b * NN + 0) * DD + d] = Hv;
        out[(b * NN + 0) * DD + d] = Hv;
        s_red[t] = Hv * lin_w[DD + d];
        __syncthreads();
        if (t < 256) s_red[t] += s_red[t + 256];
        __syncthreads();
        if (t < 128) s_red[t] += s_red[t + 128];
        __syncthreads();
        if (t < 64) {
            float p = s_red[t] + s_red[t + 64];
            #pragma unroll
            for (int off = 32; off; off >>= 1) p += __shfl_down(p, off, 64);
            if (t == 0) hk[b * NN + 0] = p;
        }
    }
    gbar(ctr, ++gen * NBLK);

    // ===== main sequential scan =====
    for (int i = 1; i < NN; ++i) {
        // ---- PhA: finish row i-1, build xblob row i, softmax, weighted sums ----
        if (blk < BB) {
            int b = blk;
            if (i >= 2) ew_row(b, i - 1, feat, bc + b * 6656, lin_w, H, out, hk, s_red);
            // xblob for row i
            {
                float x = feat[(b * NN + i) * DD + t];
                u16 h = f2b(x);
                xblob[b * 1536 + t] = h;
                xblob[b * 1536 + 512 + t] = f2b(x - b2f(h));
                xblob[b * 1536 + 1024 + t] = h;
            }
            // softmax over valid past positions
            if (t < NN) {
                float a = -1e30f;
                if (t < i && adj[(b * NN + i) * NN + t] != 0)
                    a = q[b * NN + i] + hk[b * NN + t];
                s_a[t] = a;
            }
            __syncthreads();
            if (t < 64) {
                float m = fmaxf(s_a[t], s_a[t + 64]);
                #pragma unroll
                for (int off = 32; off; off >>= 1) m = fmaxf(m, __shfl_xor(m, off, 64));
                if (t == 0) s_scal = m;
            }
            __syncthreads();
            if (t < NN) s_a[t] = __expf(s_a[t] - s_scal);
            __syncthreads();
            if (t < 64) {
                float ss = s_a[t] + s_a[t + 64];
                #pragma unroll
                for (int off = 32; off; off >>= 1) ss += __shfl_xor(ss, off, 64);
                if (t == 0) s_scal = 1.0f / ss;
            }
            __syncthreads();
            if (t < NN) {
                float w = s_a[t] * s_scal;
                s_w[t] = w;
                s_ws[t] = w * (float)smask[(b * NN + i) * NN + t];
            }
            __syncthreads();
            // u0 = sum w*s*H ; u1 = (sum w*H) - u0 ; store hi/lo segs
            {
                int d = t;
                float u0 = 0.f, ut = 0.f;
                const float* Hb = H + b * NN * DD + d;
                int n = 0;
                for (; n + 4 <= i; n += 4) {
                    float h0 = Hb[(n + 0) * DD], h1 = Hb[(n + 1) * DD];
                    float h2 = Hb[(n + 2) * DD], h3 = Hb[(n + 3) * DD];
                    u0 += s_ws[n] * h0 + s_ws[n + 1] * h1 + s_ws[n + 2] * h2 + s_ws[n + 3] * h3;
                    ut += s_w[n] * h0 + s_w[n + 1] * h1 + s_w[n + 2] * h2 + s_w[n + 3] * h3;
                }
                for (; n < i; ++n) { float h0 = Hb[n * DD]; u0 += s_ws[n] * h0; ut += s_w[n] * h0; }
                float u1 = ut - u0;
                u16 h0v = f2b(u0);
                ublob[b * 3072 + d] = h0v;
                ublob[b * 3072 + 512 + d] = f2b(u0 - b2f(h0v));
                ublob[b * 3072 + 1024 + d] = h0v;
                u16 h1v = f2b(u1);
                ublob[b * 3072 + 1536 + d] = h1v;
                ublob[b * 3072 + 2048 + d] = f2b(u1 - b2f(h1v));
                ublob[b * 3072 + 2560 + d] = h1v;
            }
        }
        gbar(ctr, ++gen * NBLK);

        // ---- PhB: M-GEMM (blocks 0-15) + x-gates row i (blocks 16-111) ----
        if (blk < 16) {
            int c0 = blk * 32;
            int m0 = (wv >> 1) * 16;
            int n0 = c0 + (wv & 1) * 16;
            int col = n0 + lr;
            f32x4 acc = {0.f, 0.f, 0.f, 0.f};
            const u16* arow = ublob + (m0 + lr) * 3072;
            const u16* brow = WrB + col * 3072;
            for (int ks = 0; ks < 96; ++ks) {
                int kb = ks * 32 + lq * 8;
                bf16x8 av = *(const bf16x8*)(arow + kb);
                bf16x8 bv = *(const bf16x8*)(brow + kb);
                acc = __builtin_amdgcn_mfma_f32_16x16x32_bf16(av, bv, acc, 0, 0, 0);
            }
            #pragma unroll
            for (int r = 0; r < 4; ++r) {
                int brw = m0 + lq * 4 + r;
                float v = acc[r];
                bc[brw * 6656 + col] = v;
                u16 h = f2b(v);
                mblob[brw * 1536 + col] = h;
                mblob[brw * 1536 + 512 + col] = f2b(v - b2f(h));
                mblob[brw * 1536 + 1024 + col] = h;
            }
        } else if (blk < 112) {
            int rb = blk - 16;
            int c0 = rb * 32;
            int m0 = (wv >> 1) * 16;
            int n0 = c0 + (wv & 1) * 16;
            int col = n0 + lr;
            f32x4 acc = {0.f, 0.f, 0.f, 0.f};
            const u16* arow = xblob + (m0 + lr) * 1536;
            const u16* brow = WxB + col * 1536;
            for (int ks = 0; ks < 48; ++ks) {
                int kb = ks * 32 + lq * 8;
                bf16x8 av = *(const bf16x8*)(arow + kb);
                bf16x8 bv = *(const bf16x8*)(brow + kb);
                acc = __builtin_amdgcn_mfma_f32_16x16x32_bf16(av, bv, acc, 0, 0, 0);
            }
            float bias = (col < TD3) ? bi_c[col] : bh_p[col - TD3];
            #pragma unroll
            for (int r = 0; r < 4; ++r) {
                int brw = m0 + lq * 4 + r;
                bc[brw * 6656 + 3584 + col] = acc[r] + bias;
            }
        }
        gbar(ctr, ++gen * NBLK);

        // ---- PhC: M-gates GEMM (blocks 0-95) ----
        if (blk < 96) {
            int c0 = blk * 32;
            int m0 = (wv >> 1) * 16;
            int n0 = c0 + (wv & 1) * 16;
            int col = n0 + lr;
            f32x4 acc = {0.f, 0.f, 0.f, 0.f};
            const u16* arow = mblob + (m0 + lr) * 1536;
            const u16* brow = WcB + col * 1536;
            for (int ks = 0; ks < 48; ++ks) {
                int kb = ks * 32 + lq * 8;
                bf16x8 av = *(const bf16x8*)(arow + kb);
                bf16x8 bv = *(const bf16x8*)(brow + kb);
                acc = __builtin_amdgcn_mfma_f32_16x16x32_bf16(av, bv, acc, 0, 0, 0);
            }
            float bias = (col < TD3) ? bh_c[col] : bi_p[col - TD3];
            #pragma unroll
            for (int r = 0; r < 4; ++r) {
                int brw = m0 + lq * 4 + r;
                bc[brw * 6656 + 512 + col] = acc[r] + bias;
            }
        }
        gbar(ctr, ++gen * NBLK);
    }

    // ---- final: row 127 ----
    if (blk < BB) {
        ew_row(blk, NN - 1, feat, bc + blk * 6656, lin_w, H, out, hk, s_red);
    }
}

extern "C" void kernel_launch(void* const* d_in, const int* in_sizes, int n_in,
                              void* d_out, int out_size, void* d_ws, size_t ws_size,
                              hipStream_t stream) {
    const float* feat = (const float*)d_in[0];
    const float* Wi_c = (const float*)d_in[1];
    const float* Wh_c = (const float*)d_in[2];
    const float* bi_c = (const float*)d_in[3];
    const float* bh_c = (const float*)d_in[4];
    const float* Wi_p = (const float*)d_in[5];
    const float* Wh_p = (const float*)d_in[6];
    const float* bi_p = (const float*)d_in[7];
    const float* bh_p = (const float*)d_in[8];
    const float* lin_w = (const float*)d_in[9];
    const float* lin_b = (const float*)d_in[10];
    const float* Wr0 = (const float*)d_in[11];
    const float* Wr1 = (const float*)d_in[12];
    const int* adj = (const int*)d_in[13];
    const int* smask = (const int*)d_in[14];
    float* out = (float*)d_out;

    char* ws = (char*)d_ws;
    size_t off = 0;
    int* ctr = (int*)(ws + off);       off += 256;
    float* H = (float*)(ws + off);     off += (size_t)BB * NN * DD * 4;   // 16.8 MB
    float* hk = (float*)(ws + off);    off += (size_t)BB * NN * 4;
    float* q = (float*)(ws + off);     off += (size_t)BB * NN * 4;
    u16* ublob = (u16*)(ws + off);     off += (size_t)BB * 3072 * 2;
    u16* mblob = (u16*)(ws + off);     off += (size_t)BB * 1536 * 2;
    u16* xblob = (u16*)(ws + off);     off += (size_t)BB * 1536 * 2;
    float* bc = (float*)(ws + off);    off += (size_t)BB * 6656 * 4;      // 1.7 MB
    u16* WrB = (u16*)(ws + off);       off += (size_t)512 * 3072 * 2;     // 3.1 MB
    u16* WcB = (u16*)(ws + off);       off += (size_t)3072 * 1536 * 2;    // 9.4 MB
    u16* WxB = (u16*)(ws + off);       off += (size_t)3072 * 1536 * 2;    // 9.4 MB

    hipMemsetAsync(d_ws, 0, 256, stream);   // reset barrier counter
    hipLaunchKernelGGL(grn_kernel, dim3(NBLK), dim3(NTHR), 0, stream,
                       feat, Wi_c, Wh_c, bi_c, bh_c, Wi_p, Wh_p, bi_p, bh_p,
                       lin_w, lin_b, Wr0, Wr1, adj, smask, out,
                       H, hk, q, ublob, mblob, xblob, bc, WrB, WcB, WxB, ctr);
}